// Round 14
// baseline (113.348 us; speedup 1.0000x reference)
//
#include <hip/hip_runtime.h>

// NVFP4 (e2m1 + e4m3 block scale) quantize-dequantize, block=16 contiguous.
// Memory-bound: 256 MiB in + 256 MiB out.
//
// Reference semantics — solved over rounds 1-13:
//  - SCALE ("A2"): s = e4m3_RNE( amax * fl32(scaling_factor/6) ), all f32.
//    (R9: A1->A2 removed the 8-round-invariant 0.4375 error = block where
//    the two argument formulas straddle an e4m3 boundary. R12==R13 shows no
//    scale-cast midpoint is active; RNE = np.round kept.)
//  - QUOTIENT: y = x * fl32(1 / scale_safe)  -- RECIPROCAL-MULTIPLY, the
//    numpy idiom `xb * (1.0 / scale_safe)` (f32 under weak-scalar rules).
//    Proven by elimination: the residual 0.21875 element is invariant to
//    f32-div-vs-exact-thresholds (R9==R12) and to every tie rule (R10-R13),
//    and a f64 ref is excluded (R2 failed). Only recip-mult differs from
//    both f32 division AND exact arithmetic on non-tie elements: fl32(1/s)
//    for the 7/2^k e4m3 family rounds UP ("001"-repeating mantissa, tail >
//    1/2 ulp), pushing a ~0.4-ulp sliver below mid*s up across the mid.
//    One such element at a 0.5-step mid with s=0.4375 => 0.21875 exactly.
//  - BINNING: searchsorted(mids, |y|, side='right') == inclusive >= against
//    literal mids (ties toward larger magnitude); clip at 6.0.
//  - OUTPUT: copysign(g*s, x); g*s exact (<=9 sig bits). r > 0 so
//    sign(y) == sign(x).

__device__ __forceinline__ float e4m3_scale(float amax, float rsix) {
    float a = amax * rsix;                // A2: single f32 multiply
    a = fminf(a, 448.0f);
    if (a == 0.0f) return 0.0f;
    unsigned bits = __float_as_uint(a);
    int e = (int)((bits >> 23) & 0xFFu) - 127;  // floor(log2(a)) for normals
    e = e < -6 ? -6 : (e > 8 ? 8 : e);
    float quantum = __uint_as_float((unsigned)((e - 3) + 127) << 23); // 2^(e-3)
    return rintf(a / quantum) * quantum;  // exact pow2 scaling + RNE (np.round)
}

__device__ __forceinline__ float fp4_one(float xv, float r, float s) {
    float y = xv * r;                     // reciprocal-multiply, f32 RNE
    float a = fminf(fabsf(y), 6.0f);
    float g = (a >= 0.25f) ? 0.5f : 0.0f; // searchsorted 'right': ties up
    g += (a >= 0.75f) ? 0.5f : 0.0f;      // grid: 0,.5,1,1.5,2,3,4,6
    g += (a >= 1.25f) ? 0.5f : 0.0f;
    g += (a >= 1.75f) ? 0.5f : 0.0f;
    g += (a >= 2.5f)  ? 1.0f : 0.0f;
    g += (a >= 3.5f)  ? 1.0f : 0.0f;
    g += (a >= 5.0f)  ? 2.0f : 0.0f;
    return copysignf(g * s, xv);          // exact product (<=9 sig bits)
}

__global__ __launch_bounds__(256) void nvfp4_qdq_kernel(
    const float* __restrict__ x, const float* __restrict__ sfp,
    float* __restrict__ out, int n4) {
    const float rsix = sfp[0] / 6.0f;     // fl32(sf/6), hoisted scalar (A2)
    const float4* __restrict__ x4 = reinterpret_cast<const float4*>(x);
    float4* __restrict__ o4 = reinterpret_cast<float4*>(out);
    const int stride = gridDim.x * blockDim.x;
    // Lane i handles float4 #i (16B, coalesced). Aligned 4-lane groups own one
    // 16-elem quant block; stride multiple of 4 keeps groups aligned.
    for (int i = blockIdx.x * blockDim.x + threadIdx.x; i < n4; i += stride) {
        float4 v = x4[i];
        float amax = fmaxf(fmaxf(fabsf(v.x), fabsf(v.y)),
                           fmaxf(fabsf(v.z), fabsf(v.w)));
        amax = fmaxf(amax, __shfl_xor(amax, 1));   // 4-lane group reduce
        amax = fmaxf(amax, __shfl_xor(amax, 2));
        const float s = e4m3_scale(amax, rsix);
        const float ssafe = (s == 0.0f) ? 1.0f : s;
        const float r = 1.0f / ssafe;     // IEEE f32 divide (no fast-math)
        float4 o;
        o.x = fp4_one(v.x, r, s);
        o.y = fp4_one(v.y, r, s);
        o.z = fp4_one(v.z, r, s);
        o.w = fp4_one(v.w, r, s);
        o4[i] = o;
    }
}

extern "C" void kernel_launch(void* const* d_in, const int* in_sizes, int n_in,
                              void* d_out, int out_size, void* d_ws, size_t ws_size,
                              hipStream_t stream) {
    const float* x = (const float*)d_in[0];
    const float* sf = (const float*)d_in[1];
    float* out = (float*)d_out;
    int n4 = out_size / 4;  // 16,777,216 float4s for 8192x8192
    int block = 256;
    int maxBlocks = 2048;   // 8 blocks/CU on 256 CUs; grid-stride covers rest
    int grid = (n4 + block - 1) / block;
    if (grid > maxBlocks) grid = maxBlocks;
    nvfp4_qdq_kernel<<<grid, block, 0, stream>>>(x, sf, out, n4);
}

// Round 15
// 104.274 us; speedup vs baseline: 1.0870x; 1.0870x over previous
//
#include <hip/hip_runtime.h>

// NVFP4 (e2m1 + e4m3 block scale) quantize-dequantize, block=16 contiguous.
// Memory-bound: 256 MiB in + 256 MiB out. PASSED R14 with absmax 0.0.
//
// Reference semantics (solved rounds 1-13, verified R14):
//  - SCALE ("A2"): s = e4m3_RNE( amax * fl32(scaling_factor/6) ), all f32.
//  - QUOTIENT: y = x * fl32(1/scale_safe)  (reciprocal-multiply; the f32
//    IEEE divide for the reciprocal is mandatory - rcp approx would break).
//  - BINNING: searchsorted(mids, |y|, side='right') == inclusive >= against
//    literal mids; clip at 6 subsumed by the >=5 threshold.
//  - OUTPUT: copysign(g*s, x); g*s exact (<=9 sig bits).
//
// R15 perf changes (semantics bit-identical):
//  - UNROLL x4 over tensor quarters: 4 independent 16B loads in flight per
//    lane, 4 independent divide chains (ILP), loop overhead /4. Lane i still
//    owns float4 i of each quarter -> stride-1 coalescing and aligned 4-lane
//    quant-block groups (q = n4/4 is a multiple of 4).
//  - Nontemporal loads/stores: touch-once streams, 512 MiB > L3.
//  - Scale path: a/quantum -> a*inv_quantum (exact pow2 mul, bit-identical;
//    kills one IEEE-divide expansion per lane-tile).

typedef float f4 __attribute__((ext_vector_type(4)));

__device__ __forceinline__ float e4m3_scale(float amax, float rsix) {
    float a = amax * rsix;                // A2: single f32 multiply
    a = fminf(a, 448.0f);
    if (a == 0.0f) return 0.0f;
    unsigned bits = __float_as_uint(a);
    int e = (int)((bits >> 23) & 0xFFu) - 127;  // floor(log2(a)) for normals
    e = e < -6 ? -6 : (e > 8 ? 8 : e);
    float quantum = __uint_as_float((unsigned)((e - 3) + 127) << 23); // 2^(e-3)
    float inv_q   = __uint_as_float((unsigned)((3 - e) + 127) << 23); // 2^(3-e)
    return rintf(a * inv_q) * quantum;    // exact pow2 scaling + RNE (np.round)
}

__device__ __forceinline__ float fp4_one(float xv, float r, float s) {
    float y = xv * r;                     // reciprocal-multiply, f32 RNE
    float a = fabsf(y);
    float g = (a >= 0.25f) ? 0.5f : 0.0f; // searchsorted 'right': ties up
    g += (a >= 0.75f) ? 0.5f : 0.0f;      // grid: 0,.5,1,1.5,2,3,4,6
    g += (a >= 1.25f) ? 0.5f : 0.0f;
    g += (a >= 1.75f) ? 0.5f : 0.0f;
    g += (a >= 2.5f)  ? 1.0f : 0.0f;
    g += (a >= 3.5f)  ? 1.0f : 0.0f;
    g += (a >= 5.0f)  ? 2.0f : 0.0f;      // >=5 -> 6 (clip subsumed)
    return copysignf(g * s, xv);          // exact product (<=9 sig bits)
}

__device__ __forceinline__ f4 tile_q(f4 v, float rsix) {
    float amax = fmaxf(fmaxf(fabsf(v[0]), fabsf(v[1])),
                       fmaxf(fabsf(v[2]), fabsf(v[3])));
    amax = fmaxf(amax, __shfl_xor(amax, 1));   // 4-lane group reduce
    amax = fmaxf(amax, __shfl_xor(amax, 2));
    const float s = e4m3_scale(amax, rsix);
    const float ssafe = (s == 0.0f) ? 1.0f : s;
    const float r = 1.0f / ssafe;              // IEEE f32 divide (required)
    f4 o;
    o[0] = fp4_one(v[0], r, s);
    o[1] = fp4_one(v[1], r, s);
    o[2] = fp4_one(v[2], r, s);
    o[3] = fp4_one(v[3], r, s);
    return o;
}

__global__ __launch_bounds__(256) void nvfp4_qdq_kernel(
    const f4* __restrict__ x4, const float* __restrict__ sfp,
    f4* __restrict__ o4, int q) {           // q = n4/4 float4s per quarter
    const float rsix = sfp[0] / 6.0f;       // fl32(sf/6), hoisted scalar (A2)
    const int stride = gridDim.x * blockDim.x;
    for (int i = blockIdx.x * blockDim.x + threadIdx.x; i < q; i += stride) {
        // 4 independent loads issued together (64B in flight per lane).
        f4 v0 = __builtin_nontemporal_load(x4 + i);
        f4 v1 = __builtin_nontemporal_load(x4 + i + q);
        f4 v2 = __builtin_nontemporal_load(x4 + i + 2 * (size_t)q);
        f4 v3 = __builtin_nontemporal_load(x4 + i + 3 * (size_t)q);
        f4 r0 = tile_q(v0, rsix);
        f4 r1 = tile_q(v1, rsix);
        f4 r2 = tile_q(v2, rsix);
        f4 r3 = tile_q(v3, rsix);
        __builtin_nontemporal_store(r0, o4 + i);
        __builtin_nontemporal_store(r1, o4 + i + q);
        __builtin_nontemporal_store(r2, o4 + i + 2 * (size_t)q);
        __builtin_nontemporal_store(r3, o4 + i + 3 * (size_t)q);
    }
}

extern "C" void kernel_launch(void* const* d_in, const int* in_sizes, int n_in,
                              void* d_out, int out_size, void* d_ws, size_t ws_size,
                              hipStream_t stream) {
    const f4* x = (const f4*)d_in[0];
    const float* sf = (const float*)d_in[1];
    f4* out = (f4*)d_out;
    int n4 = out_size / 4;   // 16,777,216 float4s for 8192x8192
    int q = n4 / 4;          // quarter size in float4s (multiple of 4)
    int block = 256;
    int maxBlocks = 2048;    // 8 wg/CU; grid-stride covers the rest
    int grid = (q + block - 1) / block;
    if (grid > maxBlocks) grid = maxBlocks;
    nvfp4_qdq_kernel<<<grid, block, 0, stream>>>(x, sf, out, q);
}